// Round 14
// baseline (738.933 us; speedup 1.0000x reference)
//
#include <hip/hip_runtime.h>

#define N     16384
#define DH    64
#define TILE  128
#define NT    (N / TILE)
#define S2    133   // padded LDS stride for the P-tile staging buffer

typedef __attribute__((ext_vector_type(8))) short  short8;
typedef __attribute__((ext_vector_type(4))) float  f32x4;

// ---- bf16 helpers (round-to-nearest-even) --------------------------------
__device__ __forceinline__ ushort bf_hi(float x) {
    unsigned u = __float_as_uint(x);
    unsigned r = u + 0x7FFFu + ((u >> 16) & 1u);
    return (ushort)(r >> 16);
}
__device__ __forceinline__ float bf_val(ushort h) {
    return __uint_as_float(((unsigned)h) << 16);
}

// per-lane 16B fragment load: 8 contiguous bf16 features of one h-row (global)
__device__ __forceinline__ short8 ldfrag(const ushort* __restrict__ p, int row, int koff) {
    return *(const short8*)(p + (size_t)row * DH + koff);
}

// ---------------------------------------------------------------------------
// Kernel 1: per-pedestrian MLP -> h split into bf16 hi/lo pair (hi+lo ~ fp32).
// ---------------------------------------------------------------------------
__global__ __launch_bounds__(128) void mlp_kernel(
    const float* __restrict__ data,
    const float* __restrict__ W1, const float* __restrict__ b1,
    const float* __restrict__ W2, const float* __restrict__ b2,
    const float* __restrict__ W3, const float* __restrict__ b3,
    ushort* __restrict__ hHi, ushort* __restrict__ hLo)
{
    __shared__ float sW1[64], sb1[32], sW2[32 * 64], sb2[64], sW3[64 * 64], sb3[64];
    const int tid = threadIdx.x;
    if (tid < 64) sW1[tid] = W1[tid];
    if (tid < 32) sb1[tid] = b1[tid];
    if (tid < 64) sb2[tid] = b2[tid];
    if (tid < 64) sb3[tid] = b3[tid];
    for (int t = tid; t < 32 * 64; t += 128) sW2[t] = W2[t];
    for (int t = tid; t < 64 * 64; t += 128) sW3[t] = W3[t];
    __syncthreads();

    const int i = blockIdx.x * 128 + tid;
    const float x0 = data[2 * i + 0];
    const float x1 = data[2 * i + 1];

    float h1[32];
#pragma unroll
    for (int o = 0; o < 32; ++o)
        h1[o] = fmaxf(0.f, fmaf(x0, sW1[o], fmaf(x1, sW1[32 + o], sb1[o])));

    float h2[64];
#pragma unroll
    for (int o = 0; o < 64; ++o) {
        float a = sb2[o];
#pragma unroll
        for (int k = 0; k < 32; ++k) a = fmaf(h1[k], sW2[k * 64 + o], a);
        h2[o] = fmaxf(0.f, a);
    }

    ushort hs[64], ls[64];
#pragma unroll
    for (int o = 0; o < 64; ++o) {
        float a = sb3[o];
#pragma unroll
        for (int k = 0; k < 64; ++k) a = fmaf(h2[k], sW3[k * 64 + o], a);
        const ushort hb = bf_hi(a);
        hs[o] = hb;
        ls[o] = bf_hi(a - bf_val(hb));
    }
#pragma unroll
    for (int q = 0; q < 8; ++q) {
        short8 vh, vl;
#pragma unroll
        for (int t = 0; t < 8; ++t) { vh[t] = (short)hs[q * 8 + t]; vl[t] = (short)ls[q * 8 + t]; }
        *(short8*)(hHi + (size_t)i * DH + q * 8) = vh;
        *(short8*)(hLo + (size_t)i * DH + q * 8) = vl;
    }
}

// ---------------------------------------------------------------------------
// B-tile staging into LDS with XOR chunk swizzle (conflict-free write+read).
// sB[arr*8192 + row*64 + 8*(q^(row&7))], q = ks*4+kb.
// ---------------------------------------------------------------------------
__device__ __forceinline__ void stage_B(
    const ushort* __restrict__ hHi, const ushort* __restrict__ hLo,
    int brow0, int tid, ushort* __restrict__ sB)
{
    const int arr = tid >> 7;        // 0 = hi, 1 = lo
    const int r   = tid & 127;
    const ushort* __restrict__ src = (arr ? hLo : hHi) + (size_t)(brow0 + r) * DH;
    ushort* __restrict__ dst = sB + arr * (TILE * DH) + r * 64;
    const int sw = (r & 7);
#pragma unroll
    for (int q = 0; q < 8; ++q) {
        const short8 v = *(const short8*)(src + q * 8);
        *(short8*)(dst + 8 * (q ^ sw)) = v;
    }
}

__device__ __forceinline__ short8 ldB(const ushort* __restrict__ sB,
                                      int arr, int row, int ks, int kb)
{
    return *(const short8*)(sB + arr * (TILE * DH) + row * 64 + 8 * (((ks << 2) + kb) ^ (row & 7)));
}

// ---------------------------------------------------------------------------
// Shared MFMA tile computation: 128x128 G-tile, 4 waves.
// Row ownership: wave w owns rows {w*16..+15} (rb=0) and {64+w*16..+15} (rb=1).
// acc[rb][cb] 16x16 fragment; C layout: col = lane&15, row = (lane>>4)*4+reg.
// G = hiA*hiB + hiA*loB + loA*hiB  (lo*lo dropped, ~2^-18 relative).
// ---------------------------------------------------------------------------
__device__ __forceinline__ void gram_tile(
    const ushort* __restrict__ hHi, const ushort* __restrict__ hLo,
    const ushort* __restrict__ sB,
    int bi, int wave, int r16, int kb, f32x4 acc[2][8])
{
#pragma unroll
    for (int rb = 0; rb < 2; ++rb)
#pragma unroll
        for (int cb = 0; cb < 8; ++cb) acc[rb][cb] = (f32x4){0.f, 0.f, 0.f, 0.f};

    const int arow = bi * TILE + wave * 16 + r16;
#pragma unroll
    for (int ks = 0; ks < 2; ++ks) {
        const int koff = ks * 32 + kb * 8;
        const short8 Ah0 = ldfrag(hHi, arow,      koff);
        const short8 Ah1 = ldfrag(hHi, arow + 64, koff);
        const short8 Al0 = ldfrag(hLo, arow,      koff);
        const short8 Al1 = ldfrag(hLo, arow + 64, koff);
#pragma unroll
        for (int cb = 0; cb < 8; ++cb) {
            const int brow = cb * 16 + r16;
            const short8 Bh = ldB(sB, 0, brow, ks, kb);
            const short8 Bl = ldB(sB, 1, brow, ks, kb);
            acc[0][cb] = __builtin_amdgcn_mfma_f32_16x16x32_bf16(Ah0, Bh, acc[0][cb], 0, 0, 0);
            acc[0][cb] = __builtin_amdgcn_mfma_f32_16x16x32_bf16(Ah0, Bl, acc[0][cb], 0, 0, 0);
            acc[0][cb] = __builtin_amdgcn_mfma_f32_16x16x32_bf16(Al0, Bh, acc[0][cb], 0, 0, 0);
            acc[1][cb] = __builtin_amdgcn_mfma_f32_16x16x32_bf16(Ah1, Bh, acc[1][cb], 0, 0, 0);
            acc[1][cb] = __builtin_amdgcn_mfma_f32_16x16x32_bf16(Ah1, Bl, acc[1][cb], 0, 0, 0);
            acc[1][cb] = __builtin_amdgcn_mfma_f32_16x16x32_bf16(Al1, Bh, acc[1][cb], 0, 0, 0);
        }
    }
}

// thread's row within the tile for (rb, reg)
__device__ __forceinline__ int tile_row(int wave, int kb, int rb, int reg) {
    return rb * 64 + wave * 16 + kb * 4 + reg;
}

// ---------------------------------------------------------------------------
// Kernel 2: pass 1, FULL GRID, multi-tile, i-side only. 1024 blocks; block =
// (bj, 16-bi chunk); XCD k owns bj band [16k,16k+16) (L2-resident). B staged
// once; per tile: gram + per-row (max, sum-exp) partials -> part_m/part_l at
// [bj*N + row]. No j-side epilogue, no second reduction.
// ---------------------------------------------------------------------------
__global__ __launch_bounds__(256, 4) void pass1_mfma(
    const ushort* __restrict__ hHi, const ushort* __restrict__ hLo,
    float* __restrict__ part_m, float* __restrict__ part_l)
{
    const int p = blockIdx.x;
    const int xcd = p & 7, slot = p >> 3;          // slot in [0, 128)
    const int bj  = xcd * 16 + (slot & 15);        // [0, 128)
    const int bi0 = (slot >> 4) * 16;              // chunk of 16 bi tiles

    const int tid = threadIdx.x;
    const int wave = tid >> 6, lane = tid & 63;
    const int r16 = lane & 15, kb = lane >> 4;

    __shared__ __attribute__((aligned(16))) ushort sB[2 * TILE * DH];  // 32 KB

    stage_B(hHi, hLo, bj * TILE, tid, sB);
    __syncthreads();

    for (int it = 0; it < 16; ++it) {
        const int bi = bi0 + it;

        f32x4 acc[2][8];
        gram_tile(hHi, hLo, sB, bi, wave, r16, kb, acc);

        // per-row (max, sum-exp) over this tile's 128 columns
#pragma unroll
        for (int rb = 0; rb < 2; ++rb) {
#pragma unroll
            for (int e = 0; e < 4; ++e) {
                float m = acc[rb][0][e];
#pragma unroll
                for (int cb = 1; cb < 8; ++cb) m = fmaxf(m, acc[rb][cb][e]);
                m = fmaxf(m, __shfl_xor(m, 1));
                m = fmaxf(m, __shfl_xor(m, 2));
                m = fmaxf(m, __shfl_xor(m, 4));
                m = fmaxf(m, __shfl_xor(m, 8));
                float s = 0.f;
#pragma unroll
                for (int cb = 0; cb < 8; ++cb) s += __expf(acc[rb][cb][e] - m);
                s += __shfl_xor(s, 1);
                s += __shfl_xor(s, 2);
                s += __shfl_xor(s, 4);
                s += __shfl_xor(s, 8);
                if (r16 == 0) {
                    const int grow = bi * TILE + tile_row(wave, kb, rb, e);
                    part_m[(size_t)bj * N + grow] = m;
                    part_l[(size_t)bj * N + grow] = s;
                }
            }
        }
    }
}

// ---------------------------------------------------------------------------
// Kernel 3: merge 128 partial (m,l) per row -> fused srow = m + ln(L).
// ---------------------------------------------------------------------------
__global__ __launch_bounds__(256) void merge_kernel(
    const float* __restrict__ part_m, const float* __restrict__ part_l,
    float* __restrict__ srow)
{
    const int i = blockIdx.x * 256 + threadIdx.x;
    float M = -3.0e38f;
    for (int o = 0; o < NT; ++o) M = fmaxf(M, part_m[(size_t)o * N + i]);
    float L = 0.f;
    for (int o = 0; o < NT; ++o)
        L = fmaf(part_l[(size_t)o * N + i], __expf(part_m[(size_t)o * N + i] - M), L);
    srow[i] = M + __logf(L);
}

// ---------------------------------------------------------------------------
// Kernel 4: pass 2, MULTI-TILE (R12, passing). 1024 blocks; block = (bj,
// 16-bi chunk). XCD k owns bj band [16k, 16k+16). B staged once; per tile:
// gram, exp(g - srow) into LDS, contiguous 512B/wave float4 NT stores.
// ---------------------------------------------------------------------------
__global__ __launch_bounds__(256, 2) void pass2_mfma(
    const ushort* __restrict__ hHi, const ushort* __restrict__ hLo,
    const float* __restrict__ srow,
    float* __restrict__ out)
{
    const int p = blockIdx.x;
    const int xcd = p & 7, slot = p >> 3;          // slot in [0, 128)
    const int bj  = xcd * 16 + (slot & 15);        // [0, 128)
    const int bi0 = (slot >> 4) * 16;              // chunk of 16 bi tiles

    const int tid = threadIdx.x;
    const int wave = tid >> 6, lane = tid & 63;
    const int r16 = lane & 15, kb = lane >> 4;

    __shared__ __attribute__((aligned(16))) ushort sB[2 * TILE * DH];  // 32 KB
    __shared__ float ldsP[64 * S2];                                    // 34 KB

    stage_B(hHi, hLo, bj * TILE, tid, sB);
    __syncthreads();

    for (int it = 0; it < 16; ++it) {
        const int bi = bi0 + it;

        f32x4 acc[2][8];
        gram_tile(hHi, hLo, sB, bi, wave, r16, kb, acc);

#pragma unroll
        for (int hh = 0; hh < 2; ++hh) {   // 64-row half; all waves active
#pragma unroll
            for (int reg = 0; reg < 4; ++reg) {
                const int rl   = wave * 16 + kb * 4 + reg;   // row within half
                const int grow = bi * TILE + hh * 64 + rl;
                const float s  = srow[grow];
#pragma unroll
                for (int cb = 0; cb < 8; ++cb)
                    ldsP[rl * S2 + cb * 16 + r16] = __expf(acc[hh][cb][reg] - s);
            }
            __syncthreads();
#pragma unroll
            for (int qq = 0; qq < 8; ++qq) {
                const int f4 = tid + 256 * qq;
                const int rl = f4 >> 5, c4 = f4 & 31;
                const f32x4 v = *(const f32x4*)&ldsP[rl * S2 + c4 * 4];
                f32x4* dst = (f32x4*)(out + (size_t)(bi * TILE + hh * 64 + rl) * N + bj * TILE + c4 * 4);
                __builtin_nontemporal_store(v, dst);
            }
            __syncthreads();   // LDS P free for next half/tile
        }
    }
}

// ---------------------------------------------------------------------------
extern "C" void kernel_launch(void* const* d_in, const int* in_sizes, int n_in,
                              void* d_out, int out_size, void* d_ws, size_t ws_size,
                              hipStream_t stream)
{
    const float* data = (const float*)d_in[0];
    const float* W1   = (const float*)d_in[1];
    const float* b1   = (const float*)d_in[2];
    const float* W2   = (const float*)d_in[3];
    const float* b2   = (const float*)d_in[4];
    const float* W3   = (const float*)d_in[5];
    const float* b3   = (const float*)d_in[6];
    float* out = (float*)d_out;

    // workspace: part_m[NT*N] | part_l[NT*N] | srow[N] | (pad N) | hHi | hLo
    float* part_m = (float*)d_ws;
    float* part_l = part_m + (size_t)NT * N;
    float* srow   = part_l + (size_t)NT * N;
    ushort* hHi   = (ushort*)(srow + 2 * N);
    ushort* hLo   = hHi + (size_t)N * DH;

    mlp_kernel<<<N / 128, 128, 0, stream>>>(data, W1, b1, W2, b2, W3, b3, hHi, hLo);
    pass1_mfma<<<1024, 256, 0, stream>>>(hHi, hLo, part_m, part_l);
    merge_kernel<<<N / 256, 256, 0, stream>>>(part_m, part_l, srow);
    pass2_mfma<<<1024, 256, 0, stream>>>(hHi, hLo, srow, out);
}

// Round 15
// 396.281 us; speedup vs baseline: 1.8647x; 1.8647x over previous
//
#include <hip/hip_runtime.h>

#define N     16384
#define DH    64
#define TILE  128
#define NT    (N / TILE)
#define S2    133   // padded LDS stride for the P-tile staging buffer

typedef __attribute__((ext_vector_type(8))) short  short8;
typedef __attribute__((ext_vector_type(4))) float  f32x4;

// ---- bf16 helpers (round-to-nearest-even) --------------------------------
__device__ __forceinline__ ushort bf_hi(float x) {
    unsigned u = __float_as_uint(x);
    unsigned r = u + 0x7FFFu + ((u >> 16) & 1u);
    return (ushort)(r >> 16);
}
__device__ __forceinline__ float bf_val(ushort h) {
    return __uint_as_float(((unsigned)h) << 16);
}

// per-lane 16B fragment load: 8 contiguous bf16 features of one h-row (global)
__device__ __forceinline__ short8 ldfrag(const ushort* __restrict__ p, int row, int koff) {
    return *(const short8*)(p + (size_t)row * DH + koff);
}

// ---------------------------------------------------------------------------
// Kernel 1: per-pedestrian MLP -> h split into bf16 hi/lo pair (hi+lo ~ fp32).
// ---------------------------------------------------------------------------
__global__ __launch_bounds__(128) void mlp_kernel(
    const float* __restrict__ data,
    const float* __restrict__ W1, const float* __restrict__ b1,
    const float* __restrict__ W2, const float* __restrict__ b2,
    const float* __restrict__ W3, const float* __restrict__ b3,
    ushort* __restrict__ hHi, ushort* __restrict__ hLo)
{
    __shared__ float sW1[64], sb1[32], sW2[32 * 64], sb2[64], sW3[64 * 64], sb3[64];
    const int tid = threadIdx.x;
    if (tid < 64) sW1[tid] = W1[tid];
    if (tid < 32) sb1[tid] = b1[tid];
    if (tid < 64) sb2[tid] = b2[tid];
    if (tid < 64) sb3[tid] = b3[tid];
    for (int t = tid; t < 32 * 64; t += 128) sW2[t] = W2[t];
    for (int t = tid; t < 64 * 64; t += 128) sW3[t] = W3[t];
    __syncthreads();

    const int i = blockIdx.x * 128 + tid;
    const float x0 = data[2 * i + 0];
    const float x1 = data[2 * i + 1];

    float h1[32];
#pragma unroll
    for (int o = 0; o < 32; ++o)
        h1[o] = fmaxf(0.f, fmaf(x0, sW1[o], fmaf(x1, sW1[32 + o], sb1[o])));

    float h2[64];
#pragma unroll
    for (int o = 0; o < 64; ++o) {
        float a = sb2[o];
#pragma unroll
        for (int k = 0; k < 32; ++k) a = fmaf(h1[k], sW2[k * 64 + o], a);
        h2[o] = fmaxf(0.f, a);
    }

    ushort hs[64], ls[64];
#pragma unroll
    for (int o = 0; o < 64; ++o) {
        float a = sb3[o];
#pragma unroll
        for (int k = 0; k < 64; ++k) a = fmaf(h2[k], sW3[k * 64 + o], a);
        const ushort hb = bf_hi(a);
        hs[o] = hb;
        ls[o] = bf_hi(a - bf_val(hb));
    }
#pragma unroll
    for (int q = 0; q < 8; ++q) {
        short8 vh, vl;
#pragma unroll
        for (int t = 0; t < 8; ++t) { vh[t] = (short)hs[q * 8 + t]; vl[t] = (short)ls[q * 8 + t]; }
        *(short8*)(hHi + (size_t)i * DH + q * 8) = vh;
        *(short8*)(hLo + (size_t)i * DH + q * 8) = vl;
    }
}

// ---------------------------------------------------------------------------
// B-tile staging into LDS with XOR chunk swizzle (conflict-free write+read).
// sB[arr*8192 + row*64 + 8*(q^(row&7))], q = ks*4+kb.
// ---------------------------------------------------------------------------
__device__ __forceinline__ void stage_B(
    const ushort* __restrict__ hHi, const ushort* __restrict__ hLo,
    int brow0, int tid, ushort* __restrict__ sB)
{
    const int arr = tid >> 7;        // 0 = hi, 1 = lo
    const int r   = tid & 127;
    const ushort* __restrict__ src = (arr ? hLo : hHi) + (size_t)(brow0 + r) * DH;
    ushort* __restrict__ dst = sB + arr * (TILE * DH) + r * 64;
    const int sw = (r & 7);
#pragma unroll
    for (int q = 0; q < 8; ++q) {
        const short8 v = *(const short8*)(src + q * 8);
        *(short8*)(dst + 8 * (q ^ sw)) = v;
    }
}

__device__ __forceinline__ short8 ldB(const ushort* __restrict__ sB,
                                      int arr, int row, int ks, int kb)
{
    return *(const short8*)(sB + arr * (TILE * DH) + row * 64 + 8 * (((ks << 2) + kb) ^ (row & 7)));
}

// ---------------------------------------------------------------------------
// Shared MFMA tile computation: 128x128 G-tile, 4 waves.
// Row ownership: wave w owns rows {w*16..+15} (rb=0) and {64+w*16..+15} (rb=1).
// acc[rb][cb] 16x16 fragment; C layout: col = lane&15, row = (lane>>4)*4+reg.
// G = hiA*hiB + hiA*loB + loA*hiB  (lo*lo dropped, ~2^-18 relative).
// ---------------------------------------------------------------------------
__device__ __forceinline__ void gram_tile(
    const ushort* __restrict__ hHi, const ushort* __restrict__ hLo,
    const ushort* __restrict__ sB,
    int bi, int wave, int r16, int kb, f32x4 acc[2][8])
{
#pragma unroll
    for (int rb = 0; rb < 2; ++rb)
#pragma unroll
        for (int cb = 0; cb < 8; ++cb) acc[rb][cb] = (f32x4){0.f, 0.f, 0.f, 0.f};

    const int arow = bi * TILE + wave * 16 + r16;
#pragma unroll
    for (int ks = 0; ks < 2; ++ks) {
        const int koff = ks * 32 + kb * 8;
        const short8 Ah0 = ldfrag(hHi, arow,      koff);
        const short8 Ah1 = ldfrag(hHi, arow + 64, koff);
        const short8 Al0 = ldfrag(hLo, arow,      koff);
        const short8 Al1 = ldfrag(hLo, arow + 64, koff);
#pragma unroll
        for (int cb = 0; cb < 8; ++cb) {
            const int brow = cb * 16 + r16;
            const short8 Bh = ldB(sB, 0, brow, ks, kb);
            const short8 Bl = ldB(sB, 1, brow, ks, kb);
            acc[0][cb] = __builtin_amdgcn_mfma_f32_16x16x32_bf16(Ah0, Bh, acc[0][cb], 0, 0, 0);
            acc[0][cb] = __builtin_amdgcn_mfma_f32_16x16x32_bf16(Ah0, Bl, acc[0][cb], 0, 0, 0);
            acc[0][cb] = __builtin_amdgcn_mfma_f32_16x16x32_bf16(Al0, Bh, acc[0][cb], 0, 0, 0);
            acc[1][cb] = __builtin_amdgcn_mfma_f32_16x16x32_bf16(Ah1, Bh, acc[1][cb], 0, 0, 0);
            acc[1][cb] = __builtin_amdgcn_mfma_f32_16x16x32_bf16(Ah1, Bl, acc[1][cb], 0, 0, 0);
            acc[1][cb] = __builtin_amdgcn_mfma_f32_16x16x32_bf16(Al1, Bh, acc[1][cb], 0, 0, 0);
        }
    }
}

// thread's row within the tile for (rb, reg)
__device__ __forceinline__ int tile_row(int wave, int kb, int rb, int reg) {
    return rb * 64 + wave * 16 + kb * 4 + reg;
}

// ---------------------------------------------------------------------------
// Kernel 2: pass 1, TRIANGLE-CHUNKED multi-tile, R12 numerics. Grid (NT, 8):
// block (bj, c) covers bi in [16c, min(16c+16, bj+1)); inactive blocks exit.
// B staged once per chunk. Per tile: gram + R12's per-tile (max, sum-exp)
// epilogues (i-side shuffle reduce; j-side shuffle + jm/jl LDS reduce).
// (256,2): no forced-VGPR-cap spill (R14 lesson).
// ---------------------------------------------------------------------------
__global__ __launch_bounds__(256, 2) void pass1_mfma(
    const ushort* __restrict__ hHi, const ushort* __restrict__ hLo,
    float* __restrict__ part_m, float* __restrict__ part_l)
{
    const int bj = blockIdx.x, c = blockIdx.y;
    if (16 * c > bj) return;
    const int bi_end = min(16 * c + 16, bj + 1);

    __shared__ __attribute__((aligned(16))) ushort sB[2 * TILE * DH];  // 32 KB
    __shared__ float jm[4 * 128], jl[4 * 128];                         //  4 KB

    const int tid = threadIdx.x;
    const int wave = tid >> 6, lane = tid & 63;
    const int r16 = lane & 15, kb = lane >> 4;

    stage_B(hHi, hLo, bj * TILE, tid, sB);
    __syncthreads();

    for (int bi = 16 * c; bi < bi_end; ++bi) {
        f32x4 acc[2][8];
        gram_tile(hHi, hLo, sB, bi, wave, r16, kb, acc);

        // ---- i-side: this thread's 8 rows over the 128 cols ----
#pragma unroll
        for (int rb = 0; rb < 2; ++rb) {
#pragma unroll
            for (int e = 0; e < 4; ++e) {
                float m = acc[rb][0][e];
#pragma unroll
                for (int cb = 1; cb < 8; ++cb) m = fmaxf(m, acc[rb][cb][e]);
                m = fmaxf(m, __shfl_xor(m, 1));
                m = fmaxf(m, __shfl_xor(m, 2));
                m = fmaxf(m, __shfl_xor(m, 4));
                m = fmaxf(m, __shfl_xor(m, 8));
                float s = 0.f;
#pragma unroll
                for (int cb = 0; cb < 8; ++cb) s += __expf(acc[rb][cb][e] - m);
                s += __shfl_xor(s, 1);
                s += __shfl_xor(s, 2);
                s += __shfl_xor(s, 4);
                s += __shfl_xor(s, 8);
                if (r16 == 0) {
                    const int grow = bi * TILE + tile_row(wave, kb, rb, e);
                    part_m[(size_t)bj * N + grow] = m;
                    part_l[(size_t)bj * N + grow] = s;
                }
            }
        }

        // ---- j-side: tile columns over cols of tile bi (off-diagonal) ----
        if (bi != bj) {
#pragma unroll
            for (int cb = 0; cb < 8; ++cb) {
                float m = acc[0][cb][0];
#pragma unroll
                for (int rb = 0; rb < 2; ++rb)
#pragma unroll
                    for (int e = 0; e < 4; ++e) m = fmaxf(m, acc[rb][cb][e]);
                m = fmaxf(m, __shfl_xor(m, 16));
                m = fmaxf(m, __shfl_xor(m, 32));
                float s = 0.f;
#pragma unroll
                for (int rb = 0; rb < 2; ++rb)
#pragma unroll
                    for (int e = 0; e < 4; ++e) s += __expf(acc[rb][cb][e] - m);
                s += __shfl_xor(s, 16);
                s += __shfl_xor(s, 32);
                if (kb == 0) { jm[wave * 128 + cb * 16 + r16] = m; jl[wave * 128 + cb * 16 + r16] = s; }
            }
            __syncthreads();
            if (tid < 128) {
                float M = jm[tid];
#pragma unroll
                for (int w = 1; w < 4; ++w) M = fmaxf(M, jm[w * 128 + tid]);
                float L = 0.f;
#pragma unroll
                for (int w = 0; w < 4; ++w) L += jl[w * 128 + tid] * __expf(jm[w * 128 + tid] - M);
                part_m[(size_t)bi * N + bj * TILE + tid] = M;
                part_l[(size_t)bi * N + bj * TILE + tid] = L;
            }
            __syncthreads();   // jm/jl free for next tile
        }
    }
}

// ---------------------------------------------------------------------------
// Kernel 3: merge 128 partial (m,l) per row -> fused srow = m + ln(L).
// ---------------------------------------------------------------------------
__global__ __launch_bounds__(256) void merge_kernel(
    const float* __restrict__ part_m, const float* __restrict__ part_l,
    float* __restrict__ srow)
{
    const int i = blockIdx.x * 256 + threadIdx.x;
    float M = -3.0e38f;
    for (int o = 0; o < NT; ++o) M = fmaxf(M, part_m[(size_t)o * N + i]);
    float L = 0.f;
    for (int o = 0; o < NT; ++o)
        L = fmaf(part_l[(size_t)o * N + i], __expf(part_m[(size_t)o * N + i] - M), L);
    srow[i] = M + __logf(L);
}

// ---------------------------------------------------------------------------
// Kernel 4: pass 2, MULTI-TILE (R12, passing). 1024 blocks; block = (bj,
// 16-bi chunk). XCD k owns bj band [16k, 16k+16). B staged once; per tile:
// gram, exp(g - srow) into LDS, contiguous 512B/wave float4 NT stores.
// ---------------------------------------------------------------------------
__global__ __launch_bounds__(256, 2) void pass2_mfma(
    const ushort* __restrict__ hHi, const ushort* __restrict__ hLo,
    const float* __restrict__ srow,
    float* __restrict__ out)
{
    const int p = blockIdx.x;
    const int xcd = p & 7, slot = p >> 3;          // slot in [0, 128)
    const int bj  = xcd * 16 + (slot & 15);        // [0, 128)
    const int bi0 = (slot >> 4) * 16;              // chunk of 16 bi tiles

    const int tid = threadIdx.x;
    const int wave = tid >> 6, lane = tid & 63;
    const int r16 = lane & 15, kb = lane >> 4;

    __shared__ __attribute__((aligned(16))) ushort sB[2 * TILE * DH];  // 32 KB
    __shared__ float ldsP[64 * S2];                                    // 34 KB

    stage_B(hHi, hLo, bj * TILE, tid, sB);
    __syncthreads();

    for (int it = 0; it < 16; ++it) {
        const int bi = bi0 + it;

        f32x4 acc[2][8];
        gram_tile(hHi, hLo, sB, bi, wave, r16, kb, acc);

#pragma unroll
        for (int hh = 0; hh < 2; ++hh) {   // 64-row half; all waves active
#pragma unroll
            for (int reg = 0; reg < 4; ++reg) {
                const int rl   = wave * 16 + kb * 4 + reg;   // row within half
                const int grow = bi * TILE + hh * 64 + rl;
                const float s  = srow[grow];
#pragma unroll
                for (int cb = 0; cb < 8; ++cb)
                    ldsP[rl * S2 + cb * 16 + r16] = __expf(acc[hh][cb][reg] - s);
            }
            __syncthreads();
#pragma unroll
            for (int qq = 0; qq < 8; ++qq) {
                const int f4 = tid + 256 * qq;
                const int rl = f4 >> 5, c4 = f4 & 31;
                const f32x4 v = *(const f32x4*)&ldsP[rl * S2 + c4 * 4];
                f32x4* dst = (f32x4*)(out + (size_t)(bi * TILE + hh * 64 + rl) * N + bj * TILE + c4 * 4);
                __builtin_nontemporal_store(v, dst);
            }
            __syncthreads();   // LDS P free for next half/tile
        }
    }
}

// ---------------------------------------------------------------------------
extern "C" void kernel_launch(void* const* d_in, const int* in_sizes, int n_in,
                              void* d_out, int out_size, void* d_ws, size_t ws_size,
                              hipStream_t stream)
{
    const float* data = (const float*)d_in[0];
    const float* W1   = (const float*)d_in[1];
    const float* b1   = (const float*)d_in[2];
    const float* W2   = (const float*)d_in[3];
    const float* b2   = (const float*)d_in[4];
    const float* W3   = (const float*)d_in[5];
    const float* b3   = (const float*)d_in[6];
    float* out = (float*)d_out;

    // workspace: part_m[NT*N] | part_l[NT*N] | srow[N] | (pad N) | hHi | hLo
    float* part_m = (float*)d_ws;
    float* part_l = part_m + (size_t)NT * N;
    float* srow   = part_l + (size_t)NT * N;
    ushort* hHi   = (ushort*)(srow + 2 * N);
    ushort* hLo   = hHi + (size_t)N * DH;

    mlp_kernel<<<N / 128, 128, 0, stream>>>(data, W1, b1, W2, b2, W3, b3, hHi, hLo);
    pass1_mfma<<<dim3(NT, 8), 256, 0, stream>>>(hHi, hLo, part_m, part_l);
    merge_kernel<<<N / 256, 256, 0, stream>>>(part_m, part_l, srow);
    pass2_mfma<<<1024, 256, 0, stream>>>(hHi, hLo, srow, out);
}

// Round 16
// 364.623 us; speedup vs baseline: 2.0266x; 1.0868x over previous
//
#include <hip/hip_runtime.h>

#define N     16384
#define DH    64
#define TILE  128
#define NT    (N / TILE)
#define S2    133   // padded LDS stride for the P-tile staging buffer

typedef __attribute__((ext_vector_type(8))) short  short8;
typedef __attribute__((ext_vector_type(4))) float  f32x4;

// ---- bf16 helpers (round-to-nearest-even) --------------------------------
__device__ __forceinline__ ushort bf_hi(float x) {
    unsigned u = __float_as_uint(x);
    unsigned r = u + 0x7FFFu + ((u >> 16) & 1u);
    return (ushort)(r >> 16);
}
__device__ __forceinline__ float bf_val(ushort h) {
    return __uint_as_float(((unsigned)h) << 16);
}

// per-lane 16B fragment load: 8 contiguous bf16 features of one h-row (global)
__device__ __forceinline__ short8 ldfrag(const ushort* __restrict__ p, int row, int koff) {
    return *(const short8*)(p + (size_t)row * DH + koff);
}

// ---------------------------------------------------------------------------
// Kernel 1: per-pedestrian MLP -> h split into bf16 hi/lo pair (hi+lo ~ fp32).
// ---------------------------------------------------------------------------
__global__ __launch_bounds__(128) void mlp_kernel(
    const float* __restrict__ data,
    const float* __restrict__ W1, const float* __restrict__ b1,
    const float* __restrict__ W2, const float* __restrict__ b2,
    const float* __restrict__ W3, const float* __restrict__ b3,
    ushort* __restrict__ hHi, ushort* __restrict__ hLo)
{
    __shared__ float sW1[64], sb1[32], sW2[32 * 64], sb2[64], sW3[64 * 64], sb3[64];
    const int tid = threadIdx.x;
    if (tid < 64) sW1[tid] = W1[tid];
    if (tid < 32) sb1[tid] = b1[tid];
    if (tid < 64) sb2[tid] = b2[tid];
    if (tid < 64) sb3[tid] = b3[tid];
    for (int t = tid; t < 32 * 64; t += 128) sW2[t] = W2[t];
    for (int t = tid; t < 64 * 64; t += 128) sW3[t] = W3[t];
    __syncthreads();

    const int i = blockIdx.x * 128 + tid;
    const float x0 = data[2 * i + 0];
    const float x1 = data[2 * i + 1];

    float h1[32];
#pragma unroll
    for (int o = 0; o < 32; ++o)
        h1[o] = fmaxf(0.f, fmaf(x0, sW1[o], fmaf(x1, sW1[32 + o], sb1[o])));

    float h2[64];
#pragma unroll
    for (int o = 0; o < 64; ++o) {
        float a = sb2[o];
#pragma unroll
        for (int k = 0; k < 32; ++k) a = fmaf(h1[k], sW2[k * 64 + o], a);
        h2[o] = fmaxf(0.f, a);
    }

    ushort hs[64], ls[64];
#pragma unroll
    for (int o = 0; o < 64; ++o) {
        float a = sb3[o];
#pragma unroll
        for (int k = 0; k < 64; ++k) a = fmaf(h2[k], sW3[k * 64 + o], a);
        const ushort hb = bf_hi(a);
        hs[o] = hb;
        ls[o] = bf_hi(a - bf_val(hb));
    }
#pragma unroll
    for (int q = 0; q < 8; ++q) {
        short8 vh, vl;
#pragma unroll
        for (int t = 0; t < 8; ++t) { vh[t] = (short)hs[q * 8 + t]; vl[t] = (short)ls[q * 8 + t]; }
        *(short8*)(hHi + (size_t)i * DH + q * 8) = vh;
        *(short8*)(hLo + (size_t)i * DH + q * 8) = vl;
    }
}

// ---------------------------------------------------------------------------
// B-tile staging into LDS with XOR chunk swizzle (conflict-free write+read).
// sB[arr*8192 + row*64 + 8*(q^(row&7))], q = ks*4+kb.
// ---------------------------------------------------------------------------
__device__ __forceinline__ void stage_B(
    const ushort* __restrict__ hHi, const ushort* __restrict__ hLo,
    int brow0, int tid, ushort* __restrict__ sB)
{
    const int arr = tid >> 7;        // 0 = hi, 1 = lo
    const int r   = tid & 127;
    const ushort* __restrict__ src = (arr ? hLo : hHi) + (size_t)(brow0 + r) * DH;
    ushort* __restrict__ dst = sB + arr * (TILE * DH) + r * 64;
    const int sw = (r & 7);
#pragma unroll
    for (int q = 0; q < 8; ++q) {
        const short8 v = *(const short8*)(src + q * 8);
        *(short8*)(dst + 8 * (q ^ sw)) = v;
    }
}

__device__ __forceinline__ short8 ldB(const ushort* __restrict__ sB,
                                      int arr, int row, int ks, int kb)
{
    return *(const short8*)(sB + arr * (TILE * DH) + row * 64 + 8 * (((ks << 2) + kb) ^ (row & 7)));
}

// ---------------------------------------------------------------------------
// Shared MFMA tile computation: 128x128 G-tile, 4 waves.
// Row ownership: wave w owns rows {w*16..+15} (rb=0) and {64+w*16..+15} (rb=1).
// acc[rb][cb] 16x16 fragment; C layout: col = lane&15, row = (lane>>4)*4+reg.
// G = hiA*hiB + hiA*loB + loA*hiB  (lo*lo dropped, ~2^-18 relative).
// ---------------------------------------------------------------------------
__device__ __forceinline__ void gram_tile(
    const ushort* __restrict__ hHi, const ushort* __restrict__ hLo,
    const ushort* __restrict__ sB,
    int bi, int wave, int r16, int kb, f32x4 acc[2][8])
{
#pragma unroll
    for (int rb = 0; rb < 2; ++rb)
#pragma unroll
        for (int cb = 0; cb < 8; ++cb) acc[rb][cb] = (f32x4){0.f, 0.f, 0.f, 0.f};

    const int arow = bi * TILE + wave * 16 + r16;
#pragma unroll
    for (int ks = 0; ks < 2; ++ks) {
        const int koff = ks * 32 + kb * 8;
        const short8 Ah0 = ldfrag(hHi, arow,      koff);
        const short8 Ah1 = ldfrag(hHi, arow + 64, koff);
        const short8 Al0 = ldfrag(hLo, arow,      koff);
        const short8 Al1 = ldfrag(hLo, arow + 64, koff);
#pragma unroll
        for (int cb = 0; cb < 8; ++cb) {
            const int brow = cb * 16 + r16;
            const short8 Bh = ldB(sB, 0, brow, ks, kb);
            const short8 Bl = ldB(sB, 1, brow, ks, kb);
            acc[0][cb] = __builtin_amdgcn_mfma_f32_16x16x32_bf16(Ah0, Bh, acc[0][cb], 0, 0, 0);
            acc[0][cb] = __builtin_amdgcn_mfma_f32_16x16x32_bf16(Ah0, Bl, acc[0][cb], 0, 0, 0);
            acc[0][cb] = __builtin_amdgcn_mfma_f32_16x16x32_bf16(Al0, Bh, acc[0][cb], 0, 0, 0);
            acc[1][cb] = __builtin_amdgcn_mfma_f32_16x16x32_bf16(Ah1, Bh, acc[1][cb], 0, 0, 0);
            acc[1][cb] = __builtin_amdgcn_mfma_f32_16x16x32_bf16(Ah1, Bl, acc[1][cb], 0, 0, 0);
            acc[1][cb] = __builtin_amdgcn_mfma_f32_16x16x32_bf16(Al1, Bh, acc[1][cb], 0, 0, 0);
        }
    }
}

// thread's row within the tile for (rb, reg)
__device__ __forceinline__ int tile_row(int wave, int kb, int rb, int reg) {
    return rb * 64 + wave * 16 + kb * 4 + reg;
}

// triangle pair decode with balanced XCD banding: p -> (bi <= bj).
__device__ __forceinline__ void tri_decode(int p, int& bi, int& bj) {
    const int xcd = p & 7, s = p >> 3;        // s in [0, 1032)
    const int q = s / 129, r = s % 129;       // q in [0,8)
    const int P = xcd * 8 + q;                // pair id in [0,64)
    if (r <= P) { bi = r;         bj = P;       }
    else        { bi = r - P - 1; bj = 127 - P; }
}

#define SMEM1_BYTES 32768   // pass1: B stage (jm/jl alias inside)

// ---------------------------------------------------------------------------
// Kernel 2: symmetric pass 1 (R12 exact: triangle, single-tile, balanced).
// Emits per-row (tile max, sum-exp) partials for both sides.
// ---------------------------------------------------------------------------
__global__ __launch_bounds__(256, 4) void pass1_mfma(
    const ushort* __restrict__ hHi, const ushort* __restrict__ hLo,
    float* __restrict__ part_m, float* __restrict__ part_l)
{
    int bi, bj;
    tri_decode(blockIdx.x, bi, bj);

    __shared__ __attribute__((aligned(16))) char smem[SMEM1_BYTES];
    ushort* sB = (ushort*)smem;
    float*  jm = (float*)smem;            // aliases sB after compute
    float*  jl = jm + 512;                // [4][128] each

    const int tid = threadIdx.x;
    const int wave = tid >> 6, lane = tid & 63;
    const int r16 = lane & 15, kb = lane >> 4;

    stage_B(hHi, hLo, bj * TILE, tid, sB);
    __syncthreads();

    f32x4 acc[2][8];
    gram_tile(hHi, hLo, sB, bi, wave, r16, kb, acc);

    // ---- i-side: this thread's 8 rows over the 128 cols ----
#pragma unroll
    for (int rb = 0; rb < 2; ++rb) {
#pragma unroll
        for (int e = 0; e < 4; ++e) {
            float m = acc[rb][0][e];
#pragma unroll
            for (int cb = 1; cb < 8; ++cb) m = fmaxf(m, acc[rb][cb][e]);
            m = fmaxf(m, __shfl_xor(m, 1));
            m = fmaxf(m, __shfl_xor(m, 2));
            m = fmaxf(m, __shfl_xor(m, 4));
            m = fmaxf(m, __shfl_xor(m, 8));
            float s = 0.f;
#pragma unroll
            for (int cb = 0; cb < 8; ++cb) s += __expf(acc[rb][cb][e] - m);
            s += __shfl_xor(s, 1);
            s += __shfl_xor(s, 2);
            s += __shfl_xor(s, 4);
            s += __shfl_xor(s, 8);
            if (r16 == 0) {
                const int grow = bi * TILE + tile_row(wave, kb, rb, e);
                part_m[(size_t)bj * N + grow] = m;
                part_l[(size_t)bj * N + grow] = s;
            }
        }
    }

    // ---- j-side: tile columns over cols of tile bi ----
    if (bi != bj) {
        __syncthreads();   // all waves done reading sB; safe to alias jm/jl
#pragma unroll
        for (int cb = 0; cb < 8; ++cb) {
            float m = acc[0][cb][0];
#pragma unroll
            for (int rb = 0; rb < 2; ++rb)
#pragma unroll
                for (int e = 0; e < 4; ++e) m = fmaxf(m, acc[rb][cb][e]);
            m = fmaxf(m, __shfl_xor(m, 16));
            m = fmaxf(m, __shfl_xor(m, 32));
            float s = 0.f;
#pragma unroll
            for (int rb = 0; rb < 2; ++rb)
#pragma unroll
                for (int e = 0; e < 4; ++e) s += __expf(acc[rb][cb][e] - m);
            s += __shfl_xor(s, 16);
            s += __shfl_xor(s, 32);
            if (kb == 0) { jm[wave * 128 + cb * 16 + r16] = m; jl[wave * 128 + cb * 16 + r16] = s; }
        }
        __syncthreads();
        if (tid < 128) {
            float M = jm[tid];
#pragma unroll
            for (int w = 1; w < 4; ++w) M = fmaxf(M, jm[w * 128 + tid]);
            float L = 0.f;
#pragma unroll
            for (int w = 0; w < 4; ++w) L += jl[w * 128 + tid] * __expf(jm[w * 128 + tid] - M);
            part_m[(size_t)bi * N + bj * TILE + tid] = M;
            part_l[(size_t)bi * N + bj * TILE + tid] = L;
        }
    }
}

// ---------------------------------------------------------------------------
// Kernel 3: merge 128 partial (m,l) per row -> fused srow = m + ln(L).
// ---------------------------------------------------------------------------
__global__ __launch_bounds__(256) void merge_kernel(
    const float* __restrict__ part_m, const float* __restrict__ part_l,
    float* __restrict__ srow)
{
    const int i = blockIdx.x * 256 + threadIdx.x;
    float M = -3.0e38f;
    for (int o = 0; o < NT; ++o) M = fmaxf(M, part_m[(size_t)o * N + i]);
    float L = 0.f;
    for (int o = 0; o < NT; ++o)
        L = fmaf(part_l[(size_t)o * N + i], __expf(part_m[(size_t)o * N + i] - M), L);
    srow[i] = M + __logf(L);
}

// ---------------------------------------------------------------------------
// Kernel 4: pass 2, MULTI-TILE, BARRIER-FREE epilogue. 1024 blocks; block =
// (bj, 16-bi chunk); XCD k owns bj band [16k,16k+16). B staged once (only
// barrier in the kernel). Each wave's output rows are entirely its own
// (hh*64 + wave*16 + kb*4 + reg), so exp->LDS->store uses a PRIVATE per-wave
// LDS slice with intra-wave ordering only. Waves drift across tiles freely,
// overlapping one wave's MFMA with another's store stream.
// ---------------------------------------------------------------------------
__global__ __launch_bounds__(256, 2) void pass2_mfma(
    const ushort* __restrict__ hHi, const ushort* __restrict__ hLo,
    const float* __restrict__ srow,
    float* __restrict__ out)
{
    const int p = blockIdx.x;
    const int xcd = p & 7, slot = p >> 3;          // slot in [0, 128)
    const int bj  = xcd * 16 + (slot & 15);        // [0, 128)
    const int bi0 = (slot >> 4) * 16;              // chunk of 16 bi tiles

    const int tid = threadIdx.x;
    const int wave = tid >> 6, lane = tid & 63;
    const int r16 = lane & 15, kb = lane >> 4;

    __shared__ __attribute__((aligned(16))) ushort sB[2 * TILE * DH];  // 32 KB
    __shared__ float ldsP[4][16 * S2];                                 // 34 KB

    stage_B(hHi, hLo, bj * TILE, tid, sB);
    __syncthreads();

    float* __restrict__ myP = &ldsP[wave][0];

    for (int it = 0; it < 16; ++it) {
        const int bi = bi0 + it;

        f32x4 acc[2][8];
        gram_tile(hHi, hLo, sB, bi, wave, r16, kb, acc);

#pragma unroll
        for (int hh = 0; hh < 2; ++hh) {
            // exp into this wave's private 16-row slice
#pragma unroll
            for (int reg = 0; reg < 4; ++reg) {
                const int rl16 = kb * 4 + reg;                     // 0..15
                const int grow = bi * TILE + hh * 64 + wave * 16 + rl16;
                const float s  = srow[grow];
#pragma unroll
                for (int cb = 0; cb < 8; ++cb)
                    myP[rl16 * S2 + cb * 16 + r16] = __expf(acc[hh][cb][reg] - s);
            }
            // store own 16 rows: 512 float4, 8 per lane (intra-wave waitcnt
            // orders the LDS reads after the writes; no barrier needed)
#pragma unroll
            for (int q = 0; q < 8; ++q) {
                const int f4 = lane + 64 * q;                      // 0..511
                const int rl16 = f4 >> 5, c4 = f4 & 31;
                const f32x4 v = *(const f32x4*)&myP[rl16 * S2 + c4 * 4];
                f32x4* dst = (f32x4*)(out + (size_t)(bi * TILE + hh * 64 + wave * 16 + rl16) * N
                                      + bj * TILE + c4 * 4);
                __builtin_nontemporal_store(v, dst);
            }
        }
    }
}

// ---------------------------------------------------------------------------
extern "C" void kernel_launch(void* const* d_in, const int* in_sizes, int n_in,
                              void* d_out, int out_size, void* d_ws, size_t ws_size,
                              hipStream_t stream)
{
    const float* data = (const float*)d_in[0];
    const float* W1   = (const float*)d_in[1];
    const float* b1   = (const float*)d_in[2];
    const float* W2   = (const float*)d_in[3];
    const float* b2   = (const float*)d_in[4];
    const float* W3   = (const float*)d_in[5];
    const float* b3   = (const float*)d_in[6];
    float* out = (float*)d_out;

    // workspace: part_m[NT*N] | part_l[NT*N] | srow[N] | (pad N) | hHi | hLo
    float* part_m = (float*)d_ws;
    float* part_l = part_m + (size_t)NT * N;
    float* srow   = part_l + (size_t)NT * N;
    ushort* hHi   = (ushort*)(srow + 2 * N);
    ushort* hLo   = hHi + (size_t)N * DH;

    mlp_kernel<<<N / 128, 128, 0, stream>>>(data, W1, b1, W2, b2, W3, b3, hHi, hLo);
    pass1_mfma<<<NT * (NT + 1) / 2, 256, 0, stream>>>(hHi, hLo, part_m, part_l);
    merge_kernel<<<N / 256, 256, 0, stream>>>(part_m, part_l, srow);
    pass2_mfma<<<1024, 256, 0, stream>>>(hHi, hLo, srow, out);
}

// Round 17
// 357.315 us; speedup vs baseline: 2.0680x; 1.0205x over previous
//
#include <hip/hip_runtime.h>

#define N     16384
#define DH    64
#define TILE  128
#define NT    (N / TILE)
#define S2    133   // padded LDS stride for the P-tile staging buffer

typedef __attribute__((ext_vector_type(8))) short  short8;
typedef __attribute__((ext_vector_type(4))) float  f32x4;

// ---- bf16 helpers (round-to-nearest-even) --------------------------------
__device__ __forceinline__ ushort bf_hi(float x) {
    unsigned u = __float_as_uint(x);
    unsigned r = u + 0x7FFFu + ((u >> 16) & 1u);
    return (ushort)(r >> 16);
}
__device__ __forceinline__ float bf_val(ushort h) {
    return __uint_as_float(((unsigned)h) << 16);
}

// per-lane 16B fragment load: 8 contiguous bf16 features of one h-row (global)
__device__ __forceinline__ short8 ldfrag(const ushort* __restrict__ p, int row, int koff) {
    return *(const short8*)(p + (size_t)row * DH + koff);
}

// ---------------------------------------------------------------------------
// Kernel 1: per-pedestrian MLP -> h split into bf16 hi/lo pair (hi+lo ~ fp32).
// ---------------------------------------------------------------------------
__global__ __launch_bounds__(128) void mlp_kernel(
    const float* __restrict__ data,
    const float* __restrict__ W1, const float* __restrict__ b1,
    const float* __restrict__ W2, const float* __restrict__ b2,
    const float* __restrict__ W3, const float* __restrict__ b3,
    ushort* __restrict__ hHi, ushort* __restrict__ hLo)
{
    __shared__ float sW1[64], sb1[32], sW2[32 * 64], sb2[64], sW3[64 * 64], sb3[64];
    const int tid = threadIdx.x;
    if (tid < 64) sW1[tid] = W1[tid];
    if (tid < 32) sb1[tid] = b1[tid];
    if (tid < 64) sb2[tid] = b2[tid];
    if (tid < 64) sb3[tid] = b3[tid];
    for (int t = tid; t < 32 * 64; t += 128) sW2[t] = W2[t];
    for (int t = tid; t < 64 * 64; t += 128) sW3[t] = W3[t];
    __syncthreads();

    const int i = blockIdx.x * 128 + tid;
    const float x0 = data[2 * i + 0];
    const float x1 = data[2 * i + 1];

    float h1[32];
#pragma unroll
    for (int o = 0; o < 32; ++o)
        h1[o] = fmaxf(0.f, fmaf(x0, sW1[o], fmaf(x1, sW1[32 + o], sb1[o])));

    float h2[64];
#pragma unroll
    for (int o = 0; o < 64; ++o) {
        float a = sb2[o];
#pragma unroll
        for (int k = 0; k < 32; ++k) a = fmaf(h1[k], sW2[k * 64 + o], a);
        h2[o] = fmaxf(0.f, a);
    }

    ushort hs[64], ls[64];
#pragma unroll
    for (int o = 0; o < 64; ++o) {
        float a = sb3[o];
#pragma unroll
        for (int k = 0; k < 64; ++k) a = fmaf(h2[k], sW3[k * 64 + o], a);
        const ushort hb = bf_hi(a);
        hs[o] = hb;
        ls[o] = bf_hi(a - bf_val(hb));
    }
#pragma unroll
    for (int q = 0; q < 8; ++q) {
        short8 vh, vl;
#pragma unroll
        for (int t = 0; t < 8; ++t) { vh[t] = (short)hs[q * 8 + t]; vl[t] = (short)ls[q * 8 + t]; }
        *(short8*)(hHi + (size_t)i * DH + q * 8) = vh;
        *(short8*)(hLo + (size_t)i * DH + q * 8) = vl;
    }
}

// ---------------------------------------------------------------------------
// B-tile staging into LDS with XOR chunk swizzle (conflict-free write+read).
// sB[arr*8192 + row*64 + 8*(q^(row&7))], q = ks*4+kb.
// ---------------------------------------------------------------------------
__device__ __forceinline__ void stage_B(
    const ushort* __restrict__ hHi, const ushort* __restrict__ hLo,
    int brow0, int tid, ushort* __restrict__ sB)
{
    const int arr = tid >> 7;        // 0 = hi, 1 = lo
    const int r   = tid & 127;
    const ushort* __restrict__ src = (arr ? hLo : hHi) + (size_t)(brow0 + r) * DH;
    ushort* __restrict__ dst = sB + arr * (TILE * DH) + r * 64;
    const int sw = (r & 7);
#pragma unroll
    for (int q = 0; q < 8; ++q) {
        const short8 v = *(const short8*)(src + q * 8);
        *(short8*)(dst + 8 * (q ^ sw)) = v;
    }
}

__device__ __forceinline__ short8 ldB(const ushort* __restrict__ sB,
                                      int arr, int row, int ks, int kb)
{
    return *(const short8*)(sB + arr * (TILE * DH) + row * 64 + 8 * (((ks << 2) + kb) ^ (row & 7)));
}

// ---------------------------------------------------------------------------
// Shared MFMA tile computation: 128x128 G-tile, 4 waves.
// Row ownership: wave w owns rows {w*16..+15} (rb=0) and {64+w*16..+15} (rb=1).
// acc[rb][cb] 16x16 fragment; C layout: col = lane&15, row = (lane>>4)*4+reg.
// G = hiA*hiB + hiA*loB + loA*hiB  (lo*lo dropped, ~2^-18 relative).
// ---------------------------------------------------------------------------
__device__ __forceinline__ void gram_tile(
    const ushort* __restrict__ hHi, const ushort* __restrict__ hLo,
    const ushort* __restrict__ sB,
    int bi, int wave, int r16, int kb, f32x4 acc[2][8])
{
#pragma unroll
    for (int rb = 0; rb < 2; ++rb)
#pragma unroll
        for (int cb = 0; cb < 8; ++cb) acc[rb][cb] = (f32x4){0.f, 0.f, 0.f, 0.f};

    const int arow = bi * TILE + wave * 16 + r16;
#pragma unroll
    for (int ks = 0; ks < 2; ++ks) {
        const int koff = ks * 32 + kb * 8;
        const short8 Ah0 = ldfrag(hHi, arow,      koff);
        const short8 Ah1 = ldfrag(hHi, arow + 64, koff);
        const short8 Al0 = ldfrag(hLo, arow,      koff);
        const short8 Al1 = ldfrag(hLo, arow + 64, koff);
#pragma unroll
        for (int cb = 0; cb < 8; ++cb) {
            const int brow = cb * 16 + r16;
            const short8 Bh = ldB(sB, 0, brow, ks, kb);
            const short8 Bl = ldB(sB, 1, brow, ks, kb);
            acc[0][cb] = __builtin_amdgcn_mfma_f32_16x16x32_bf16(Ah0, Bh, acc[0][cb], 0, 0, 0);
            acc[0][cb] = __builtin_amdgcn_mfma_f32_16x16x32_bf16(Ah0, Bl, acc[0][cb], 0, 0, 0);
            acc[0][cb] = __builtin_amdgcn_mfma_f32_16x16x32_bf16(Al0, Bh, acc[0][cb], 0, 0, 0);
            acc[1][cb] = __builtin_amdgcn_mfma_f32_16x16x32_bf16(Ah1, Bh, acc[1][cb], 0, 0, 0);
            acc[1][cb] = __builtin_amdgcn_mfma_f32_16x16x32_bf16(Ah1, Bl, acc[1][cb], 0, 0, 0);
            acc[1][cb] = __builtin_amdgcn_mfma_f32_16x16x32_bf16(Al1, Bh, acc[1][cb], 0, 0, 0);
        }
    }
}

// thread's row within the tile for (rb, reg)
__device__ __forceinline__ int tile_row(int wave, int kb, int rb, int reg) {
    return rb * 64 + wave * 16 + kb * 4 + reg;
}

// triangle pair decode with balanced XCD banding: p -> (bi <= bj).
__device__ __forceinline__ void tri_decode(int p, int& bi, int& bj) {
    const int xcd = p & 7, s = p >> 3;        // s in [0, 1032)
    const int q = s / 129, r = s % 129;       // q in [0,8)
    const int P = xcd * 8 + q;                // pair id in [0,64)
    if (r <= P) { bi = r;         bj = P;       }
    else        { bi = r - P - 1; bj = 127 - P; }
}

#define SMEM1_BYTES 32768   // pass1: B stage (jm/jl alias inside)

// ---------------------------------------------------------------------------
// Kernel 2: symmetric pass 1 (R12 exact: triangle, single-tile, balanced).
// Emits per-row (tile max, sum-exp) partials for both sides.
// ---------------------------------------------------------------------------
__global__ __launch_bounds__(256, 4) void pass1_mfma(
    const ushort* __restrict__ hHi, const ushort* __restrict__ hLo,
    float* __restrict__ part_m, float* __restrict__ part_l)
{
    int bi, bj;
    tri_decode(blockIdx.x, bi, bj);

    __shared__ __attribute__((aligned(16))) char smem[SMEM1_BYTES];
    ushort* sB = (ushort*)smem;
    float*  jm = (float*)smem;            // aliases sB after compute
    float*  jl = jm + 512;                // [4][128] each

    const int tid = threadIdx.x;
    const int wave = tid >> 6, lane = tid & 63;
    const int r16 = lane & 15, kb = lane >> 4;

    stage_B(hHi, hLo, bj * TILE, tid, sB);
    __syncthreads();

    f32x4 acc[2][8];
    gram_tile(hHi, hLo, sB, bi, wave, r16, kb, acc);

    // ---- i-side: this thread's 8 rows over the 128 cols ----
#pragma unroll
    for (int rb = 0; rb < 2; ++rb) {
#pragma unroll
        for (int e = 0; e < 4; ++e) {
            float m = acc[rb][0][e];
#pragma unroll
            for (int cb = 1; cb < 8; ++cb) m = fmaxf(m, acc[rb][cb][e]);
            m = fmaxf(m, __shfl_xor(m, 1));
            m = fmaxf(m, __shfl_xor(m, 2));
            m = fmaxf(m, __shfl_xor(m, 4));
            m = fmaxf(m, __shfl_xor(m, 8));
            float s = 0.f;
#pragma unroll
            for (int cb = 0; cb < 8; ++cb) s += __expf(acc[rb][cb][e] - m);
            s += __shfl_xor(s, 1);
            s += __shfl_xor(s, 2);
            s += __shfl_xor(s, 4);
            s += __shfl_xor(s, 8);
            if (r16 == 0) {
                const int grow = bi * TILE + tile_row(wave, kb, rb, e);
                part_m[(size_t)bj * N + grow] = m;
                part_l[(size_t)bj * N + grow] = s;
            }
        }
    }

    // ---- j-side: tile columns over cols of tile bi ----
    if (bi != bj) {
        __syncthreads();   // all waves done reading sB; safe to alias jm/jl
#pragma unroll
        for (int cb = 0; cb < 8; ++cb) {
            float m = acc[0][cb][0];
#pragma unroll
            for (int rb = 0; rb < 2; ++rb)
#pragma unroll
                for (int e = 0; e < 4; ++e) m = fmaxf(m, acc[rb][cb][e]);
            m = fmaxf(m, __shfl_xor(m, 16));
            m = fmaxf(m, __shfl_xor(m, 32));
            float s = 0.f;
#pragma unroll
            for (int rb = 0; rb < 2; ++rb)
#pragma unroll
                for (int e = 0; e < 4; ++e) s += __expf(acc[rb][cb][e] - m);
            s += __shfl_xor(s, 16);
            s += __shfl_xor(s, 32);
            if (kb == 0) { jm[wave * 128 + cb * 16 + r16] = m; jl[wave * 128 + cb * 16 + r16] = s; }
        }
        __syncthreads();
        if (tid < 128) {
            float M = jm[tid];
#pragma unroll
            for (int w = 1; w < 4; ++w) M = fmaxf(M, jm[w * 128 + tid]);
            float L = 0.f;
#pragma unroll
            for (int w = 0; w < 4; ++w) L += jl[w * 128 + tid] * __expf(jm[w * 128 + tid] - M);
            part_m[(size_t)bi * N + bj * TILE + tid] = M;
            part_l[(size_t)bi * N + bj * TILE + tid] = L;
        }
    }
}

// ---------------------------------------------------------------------------
// Kernel 3: merge 128 partial (m,l) per row -> fused srow = m + ln(L).
// ---------------------------------------------------------------------------
__global__ __launch_bounds__(256) void merge_kernel(
    const float* __restrict__ part_m, const float* __restrict__ part_l,
    float* __restrict__ srow)
{
    const int i = blockIdx.x * 256 + threadIdx.x;
    float M = -3.0e38f;
    for (int o = 0; o < NT; ++o) M = fmaxf(M, part_m[(size_t)o * N + i]);
    float L = 0.f;
    for (int o = 0; o < NT; ++o)
        L = fmaf(part_l[(size_t)o * N + i], __expf(part_m[(size_t)o * N + i] - M), L);
    srow[i] = M + __logf(L);
}

// ---------------------------------------------------------------------------
// Kernel 4: pass 2, MULTI-TILE (R12 structure, chunk widened 16->32).
// 512 blocks; block = (bj, 32-bi chunk); XCD k owns bj band [16k,16k+16).
// Exactly 2 resident generations per CU, zero tail, uniform work. B staged
// once; per tile: gram, exp(g - srow) into LDS, contiguous 512B/wave float4
// nontemporal stores.
// ---------------------------------------------------------------------------
__global__ __launch_bounds__(256, 2) void pass2_mfma(
    const ushort* __restrict__ hHi, const ushort* __restrict__ hLo,
    const float* __restrict__ srow,
    float* __restrict__ out)
{
    const int p = blockIdx.x;
    const int xcd = p & 7, slot = p >> 3;          // slot in [0, 64)
    const int bj  = xcd * 16 + (slot & 15);        // [0, 128)
    const int bi0 = (slot >> 4) * 32;              // chunk of 32 bi tiles

    const int tid = threadIdx.x;
    const int wave = tid >> 6, lane = tid & 63;
    const int r16 = lane & 15, kb = lane >> 4;

    __shared__ __attribute__((aligned(16))) ushort sB[2 * TILE * DH];  // 32 KB
    __shared__ float ldsP[64 * S2];                                    // 34 KB

    stage_B(hHi, hLo, bj * TILE, tid, sB);
    __syncthreads();

    for (int it = 0; it < 32; ++it) {
        const int bi = bi0 + it;

        f32x4 acc[2][8];
        gram_tile(hHi, hLo, sB, bi, wave, r16, kb, acc);

#pragma unroll
        for (int hh = 0; hh < 2; ++hh) {   // 64-row half; all waves active
#pragma unroll
            for (int reg = 0; reg < 4; ++reg) {
                const int rl   = wave * 16 + kb * 4 + reg;   // row within half
                const int grow = bi * TILE + hh * 64 + rl;
                const float s  = srow[grow];
#pragma unroll
                for (int cb = 0; cb < 8; ++cb)
                    ldsP[rl * S2 + cb * 16 + r16] = __expf(acc[hh][cb][reg] - s);
            }
            __syncthreads();
#pragma unroll
            for (int qq = 0; qq < 8; ++qq) {
                const int f4 = tid + 256 * qq;
                const int rl = f4 >> 5, c4 = f4 & 31;
                const f32x4 v = *(const f32x4*)&ldsP[rl * S2 + c4 * 4];
                f32x4* dst = (f32x4*)(out + (size_t)(bi * TILE + hh * 64 + rl) * N + bj * TILE + c4 * 4);
                __builtin_nontemporal_store(v, dst);
            }
            __syncthreads();   // LDS P free for next half/tile
        }
    }
}

// ---------------------------------------------------------------------------
extern "C" void kernel_launch(void* const* d_in, const int* in_sizes, int n_in,
                              void* d_out, int out_size, void* d_ws, size_t ws_size,
                              hipStream_t stream)
{
    const float* data = (const float*)d_in[0];
    const float* W1   = (const float*)d_in[1];
    const float* b1   = (const float*)d_in[2];
    const float* W2   = (const float*)d_in[3];
    const float* b2   = (const float*)d_in[4];
    const float* W3   = (const float*)d_in[5];
    const float* b3   = (const float*)d_in[6];
    float* out = (float*)d_out;

    // workspace: part_m[NT*N] | part_l[NT*N] | srow[N] | (pad N) | hHi | hLo
    float* part_m = (float*)d_ws;
    float* part_l = part_m + (size_t)NT * N;
    float* srow   = part_l + (size_t)NT * N;
    ushort* hHi   = (ushort*)(srow + 2 * N);
    ushort* hLo   = hHi + (size_t)N * DH;

    mlp_kernel<<<N / 128, 128, 0, stream>>>(data, W1, b1, W2, b2, W3, b3, hHi, hLo);
    pass1_mfma<<<NT * (NT + 1) / 2, 256, 0, stream>>>(hHi, hLo, part_m, part_l);
    merge_kernel<<<N / 256, 256, 0, stream>>>(part_m, part_l, srow);
    pass2_mfma<<<512, 256, 0, stream>>>(hHi, hLo, srow, out);
}

// Round 19
// 356.462 us; speedup vs baseline: 2.0730x; 1.0024x over previous
//
#include <hip/hip_runtime.h>

#define N     16384
#define DH    64
#define TILE  128
#define NT    (N / TILE)
#define S2    133   // padded LDS stride for the P-tile staging buffer

typedef __attribute__((ext_vector_type(8))) short  short8;
typedef __attribute__((ext_vector_type(4))) float  f32x4;

// ---- bf16 helpers (round-to-nearest-even) --------------------------------
__device__ __forceinline__ ushort bf_hi(float x) {
    unsigned u = __float_as_uint(x);
    unsigned r = u + 0x7FFFu + ((u >> 16) & 1u);
    return (ushort)(r >> 16);
}
__device__ __forceinline__ float bf_val(ushort h) {
    return __uint_as_float(((unsigned)h) << 16);
}

// per-lane 16B fragment load: 8 contiguous bf16 features of one h-row (global)
__device__ __forceinline__ short8 ldfrag(const ushort* __restrict__ p, int row, int koff) {
    return *(const short8*)(p + (size_t)row * DH + koff);
}

// ---------------------------------------------------------------------------
// Kernel 1: per-pedestrian MLP -> h split into bf16 hi/lo pair (hi+lo ~ fp32).
// ---------------------------------------------------------------------------
__global__ __launch_bounds__(128) void mlp_kernel(
    const float* __restrict__ data,
    const float* __restrict__ W1, const float* __restrict__ b1,
    const float* __restrict__ W2, const float* __restrict__ b2,
    const float* __restrict__ W3, const float* __restrict__ b3,
    ushort* __restrict__ hHi, ushort* __restrict__ hLo)
{
    __shared__ float sW1[64], sb1[32], sW2[32 * 64], sb2[64], sW3[64 * 64], sb3[64];
    const int tid = threadIdx.x;
    if (tid < 64) sW1[tid] = W1[tid];
    if (tid < 32) sb1[tid] = b1[tid];
    if (tid < 64) sb2[tid] = b2[tid];
    if (tid < 64) sb3[tid] = b3[tid];
    for (int t = tid; t < 32 * 64; t += 128) sW2[t] = W2[t];
    for (int t = tid; t < 64 * 64; t += 128) sW3[t] = W3[t];
    __syncthreads();

    const int i = blockIdx.x * 128 + tid;
    const float x0 = data[2 * i + 0];
    const float x1 = data[2 * i + 1];

    float h1[32];
#pragma unroll
    for (int o = 0; o < 32; ++o)
        h1[o] = fmaxf(0.f, fmaf(x0, sW1[o], fmaf(x1, sW1[32 + o], sb1[o])));

    float h2[64];
#pragma unroll
    for (int o = 0; o < 64; ++o) {
        float a = sb2[o];
#pragma unroll
        for (int k = 0; k < 32; ++k) a = fmaf(h1[k], sW2[k * 64 + o], a);
        h2[o] = fmaxf(0.f, a);
    }

    ushort hs[64], ls[64];
#pragma unroll
    for (int o = 0; o < 64; ++o) {
        float a = sb3[o];
#pragma unroll
        for (int k = 0; k < 64; ++k) a = fmaf(h2[k], sW3[k * 64 + o], a);
        const ushort hb = bf_hi(a);
        hs[o] = hb;
        ls[o] = bf_hi(a - bf_val(hb));
    }
#pragma unroll
    for (int q = 0; q < 8; ++q) {
        short8 vh, vl;
#pragma unroll
        for (int t = 0; t < 8; ++t) { vh[t] = (short)hs[q * 8 + t]; vl[t] = (short)ls[q * 8 + t]; }
        *(short8*)(hHi + (size_t)i * DH + q * 8) = vh;
        *(short8*)(hLo + (size_t)i * DH + q * 8) = vl;
    }
}

// ---------------------------------------------------------------------------
// B-tile staging into LDS with XOR chunk swizzle (conflict-free write+read).
// sB[arr*8192 + row*64 + 8*(q^(row&7))], q = ks*4+kb.
// ---------------------------------------------------------------------------
__device__ __forceinline__ void stage_B(
    const ushort* __restrict__ hHi, const ushort* __restrict__ hLo,
    int brow0, int tid, ushort* __restrict__ sB)
{
    const int arr = tid >> 7;        // 0 = hi, 1 = lo
    const int r   = tid & 127;
    const ushort* __restrict__ src = (arr ? hLo : hHi) + (size_t)(brow0 + r) * DH;
    ushort* __restrict__ dst = sB + arr * (TILE * DH) + r * 64;
    const int sw = (r & 7);
#pragma unroll
    for (int q = 0; q < 8; ++q) {
        const short8 v = *(const short8*)(src + q * 8);
        *(short8*)(dst + 8 * (q ^ sw)) = v;
    }
}

__device__ __forceinline__ short8 ldB(const ushort* __restrict__ sB,
                                      int arr, int row, int ks, int kb)
{
    return *(const short8*)(sB + arr * (TILE * DH) + row * 64 + 8 * (((ks << 2) + kb) ^ (row & 7)));
}

// ---------------------------------------------------------------------------
// Shared MFMA tile computation: 128x128 G-tile, 4 waves.
// Row ownership: wave w owns rows {w*16..+15} (rb=0) and {64+w*16..+15} (rb=1).
// ks hoisted for low A liveness. acc[rb][cb] 16x16 fragment;
// C layout: col = lane&15, row = (lane>>4)*4+reg.
// G = hiA*hiB + hiA*loB + loA*hiB  (lo*lo dropped, ~2^-18 relative).
// ---------------------------------------------------------------------------
__device__ __forceinline__ void gram_tile(
    const ushort* __restrict__ hHi, const ushort* __restrict__ hLo,
    const ushort* __restrict__ sB,
    int bi, int wave, int r16, int kb, f32x4 acc[2][8])
{
#pragma unroll
    for (int rb = 0; rb < 2; ++rb)
#pragma unroll
        for (int cb = 0; cb < 8; ++cb) acc[rb][cb] = (f32x4){0.f, 0.f, 0.f, 0.f};

    const int arow = bi * TILE + wave * 16 + r16;
#pragma unroll
    for (int ks = 0; ks < 2; ++ks) {
        const int koff = ks * 32 + kb * 8;
        const short8 Ah0 = ldfrag(hHi, arow,      koff);
        const short8 Ah1 = ldfrag(hHi, arow + 64, koff);
        const short8 Al0 = ldfrag(hLo, arow,      koff);
        const short8 Al1 = ldfrag(hLo, arow + 64, koff);
#pragma unroll
        for (int cb = 0; cb < 8; ++cb) {
            const int brow = cb * 16 + r16;
            const short8 Bh = ldB(sB, 0, brow, ks, kb);
            const short8 Bl = ldB(sB, 1, brow, ks, kb);
            acc[0][cb] = __builtin_amdgcn_mfma_f32_16x16x32_bf16(Ah0, Bh, acc[0][cb], 0, 0, 0);
            acc[0][cb] = __builtin_amdgcn_mfma_f32_16x16x32_bf16(Ah0, Bl, acc[0][cb], 0, 0, 0);
            acc[0][cb] = __builtin_amdgcn_mfma_f32_16x16x32_bf16(Al0, Bh, acc[0][cb], 0, 0, 0);
            acc[1][cb] = __builtin_amdgcn_mfma_f32_16x16x32_bf16(Ah1, Bh, acc[1][cb], 0, 0, 0);
            acc[1][cb] = __builtin_amdgcn_mfma_f32_16x16x32_bf16(Ah1, Bl, acc[1][cb], 0, 0, 0);
            acc[1][cb] = __builtin_amdgcn_mfma_f32_16x16x32_bf16(Al1, Bh, acc[1][cb], 0, 0, 0);
        }
    }
}

// thread's row within the pass1 tile for (rb, reg)
__device__ __forceinline__ int tile_row(int wave, int kb, int rb, int reg) {
    return rb * 64 + wave * 16 + kb * 4 + reg;
}

// triangle pair decode with balanced XCD banding: p -> (bi <= bj).
__device__ __forceinline__ void tri_decode(int p, int& bi, int& bj) {
    const int xcd = p & 7, s = p >> 3;        // s in [0, 1032)
    const int q = s / 129, r = s % 129;       // q in [0,8)
    const int P = xcd * 8 + q;                // pair id in [0,64)
    if (r <= P) { bi = r;         bj = P;       }
    else        { bi = r - P - 1; bj = 127 - P; }
}

#define SMEM1_BYTES 32768   // pass1: B stage (jm/jl alias inside)

// ---------------------------------------------------------------------------
// Kernel 2: symmetric pass 1 (triangle, single-tile, balanced). Emits per-row
// (tile max, sum-exp) partials for both sides.
// ---------------------------------------------------------------------------
__global__ __launch_bounds__(256, 4) void pass1_mfma(
    const ushort* __restrict__ hHi, const ushort* __restrict__ hLo,
    float* __restrict__ part_m, float* __restrict__ part_l)
{
    int bi, bj;
    tri_decode(blockIdx.x, bi, bj);

    __shared__ __attribute__((aligned(16))) char smem[SMEM1_BYTES];
    ushort* sB = (ushort*)smem;
    float*  jm = (float*)smem;            // aliases sB after compute
    float*  jl = jm + 512;                // [4][128] each

    const int tid = threadIdx.x;
    const int wave = tid >> 6, lane = tid & 63;
    const int r16 = lane & 15, kb = lane >> 4;

    stage_B(hHi, hLo, bj * TILE, tid, sB);
    __syncthreads();

    f32x4 acc[2][8];
    gram_tile(hHi, hLo, sB, bi, wave, r16, kb, acc);

    // ---- i-side: this thread's 8 rows over the 128 cols ----
#pragma unroll
    for (int rb = 0; rb < 2; ++rb) {
#pragma unroll
        for (int e = 0; e < 4; ++e) {
            float m = acc[rb][0][e];
#pragma unroll
            for (int cb = 1; cb < 8; ++cb) m = fmaxf(m, acc[rb][cb][e]);
            m = fmaxf(m, __shfl_xor(m, 1));
            m = fmaxf(m, __shfl_xor(m, 2));
            m = fmaxf(m, __shfl_xor(m, 4));
            m = fmaxf(m, __shfl_xor(m, 8));
            float s = 0.f;
#pragma unroll
            for (int cb = 0; cb < 8; ++cb) s += __expf(acc[rb][cb][e] - m);
            s += __shfl_xor(s, 1);
            s += __shfl_xor(s, 2);
            s += __shfl_xor(s, 4);
            s += __shfl_xor(s, 8);
            if (r16 == 0) {
                const int grow = bi * TILE + tile_row(wave, kb, rb, e);
                part_m[(size_t)bj * N + grow] = m;
                part_l[(size_t)bj * N + grow] = s;
            }
        }
    }

    // ---- j-side: tile columns over cols of tile bi ----
    if (bi != bj) {
        __syncthreads();   // all waves done reading sB; safe to alias jm/jl
#pragma unroll
        for (int cb = 0; cb < 8; ++cb) {
            float m = acc[0][cb][0];
#pragma unroll
            for (int rb = 0; rb < 2; ++rb)
#pragma unroll
                for (int e = 0; e < 4; ++e) m = fmaxf(m, acc[rb][cb][e]);
            m = fmaxf(m, __shfl_xor(m, 16));
            m = fmaxf(m, __shfl_xor(m, 32));
            float s = 0.f;
#pragma unroll
            for (int rb = 0; rb < 2; ++rb)
#pragma unroll
                for (int e = 0; e < 4; ++e) s += __expf(acc[rb][cb][e] - m);
            s += __shfl_xor(s, 16);
            s += __shfl_xor(s, 32);
            if (kb == 0) { jm[wave * 128 + cb * 16 + r16] = m; jl[wave * 128 + cb * 16 + r16] = s; }
        }
        __syncthreads();
        if (tid < 128) {
            float M = jm[tid];
#pragma unroll
            for (int w = 1; w < 4; ++w) M = fmaxf(M, jm[w * 128 + tid]);
            float L = 0.f;
#pragma unroll
            for (int w = 0; w < 4; ++w) L += jl[w * 128 + tid] * __expf(jm[w * 128 + tid] - M);
            part_m[(size_t)bi * N + bj * TILE + tid] = M;
            part_l[(size_t)bi * N + bj * TILE + tid] = L;
        }
    }
}

// ---------------------------------------------------------------------------
// Kernel 3: merge 128 partial (m,l) per row -> fused srow = m + ln(L).
// pass2 then computes P = exp(g - srow): one stat load, no multiply.
// ---------------------------------------------------------------------------
__global__ __launch_bounds__(256) void merge_kernel(
    const float* __restrict__ part_m, const float* __restrict__ part_l,
    float* __restrict__ srow)
{
    const int i = blockIdx.x * 256 + threadIdx.x;
    float M = -3.0e38f;
    for (int o = 0; o < NT; ++o) M = fmaxf(M, part_m[(size_t)o * N + i]);
    float L = 0.f;
    for (int o = 0; o < NT; ++o)
        L = fmaf(part_l[(size_t)o * N + i], __expf(part_m[(size_t)o * N + i] - M), L);
    srow[i] = M + __logf(L);
}

// ---------------------------------------------------------------------------
// Kernel 4: pass 2, MULTI-TILE. 1024 blocks; block = (bj, 16-tile bi chunk).
// XCD k owns bj band [16k, 16k+16) (512 KB, L2-resident). B staged ONCE per
// block, then 16 tiles of {gram, exp(g-s) into LDS, contiguous 512B/wave
// float4 nontemporal stores}. LDS = B 32KB + P 34KB (no aliasing).
// ---------------------------------------------------------------------------
__global__ __launch_bounds__(256, 2) void pass2_mfma(
    const ushort* __restrict__ hHi, const ushort* __restrict__ hLo,
    const float* __restrict__ srow,
    float* __restrict__ out)
{
    const int p = blockIdx.x;
    const int xcd = p & 7, slot = p >> 3;          // slot in [0, 128)
    const int bj  = xcd * 16 + (slot & 15);        // [0, 128)
    const int bi0 = (slot >> 4) * 16;              // chunk of 16 bi tiles

    const int tid = threadIdx.x;
    const int wave = tid >> 6, lane = tid & 63;
    const int r16 = lane & 15, kb = lane >> 4;

    __shared__ __attribute__((aligned(16))) ushort sB[2 * TILE * DH];  // 32 KB
    __shared__ float ldsP[64 * S2];                                    // 34 KB

    stage_B(hHi, hLo, bj * TILE, tid, sB);
    __syncthreads();

    for (int it = 0; it < 16; ++it) {
        const int bi = bi0 + it;

        f32x4 acc[2][8];
        gram_tile(hHi, hLo, sB, bi, wave, r16, kb, acc);

#pragma unroll
        for (int hh = 0; hh < 2; ++hh) {   // 64-row half; all waves active
#pragma unroll
            for (int reg = 0; reg < 4; ++reg) {
                const int rl   = wave * 16 + kb * 4 + reg;   // row within half
                const int grow = bi * TILE + hh * 64 + rl;
                const float s  = srow[grow];
#pragma unroll
                for (int cb = 0; cb < 8; ++cb)
                    ldsP[rl * S2 + cb * 16 + r16] = __expf(acc[hh][cb][reg] - s);
            }
            __syncthreads();
            // coalesced streaming store: 2048 float4 = 64 rows x 32 float4
#pragma unroll
            for (int qq = 0; qq < 8; ++qq) {
                const int f4 = tid + 256 * qq;
                const int rl = f4 >> 5, c4 = f4 & 31;
                const f32x4 v = *(const f32x4*)&ldsP[rl * S2 + c4 * 4];
                f32x4* dst = (f32x4*)(out + (size_t)(bi * TILE + hh * 64 + rl) * N + bj * TILE + c4 * 4);
                __builtin_nontemporal_store(v, dst);
            }
            __syncthreads();   // LDS P free for next half/tile
        }
    }
}

// ---------------------------------------------------------------------------
extern "C" void kernel_launch(void* const* d_in, const int* in_sizes, int n_in,
                              void* d_out, int out_size, void* d_ws, size_t ws_size,
                              hipStream_t stream)
{
    const float* data = (const float*)d_in[0];
    const float* W1   = (const float*)d_in[1];
    const float* b1   = (const float*)d_in[2];
    const float* W2   = (const float*)d_in[3];
    const float* b2   = (const float*)d_in[4];
    const float* W3   = (const float*)d_in[5];
    const float* b3   = (const float*)d_in[6];
    float* out = (float*)d_out;

    // workspace: part_m[NT*N] | part_l[NT*N] | srow[N] | (pad N) | hHi | hLo
    float* part_m = (float*)d_ws;
    float* part_l = part_m + (size_t)NT * N;
    float* srow   = part_l + (size_t)NT * N;
    ushort* hHi   = (ushort*)(srow + 2 * N);
    ushort* hLo   = hHi + (size_t)N * DH;

    mlp_kernel<<<N / 128, 128, 0, stream>>>(data, W1, b1, W2, b2, W3, b3, hHi, hLo);
    pass1_mfma<<<NT * (NT + 1) / 2, 256, 0, stream>>>(hHi, hLo, part_m, part_l);
    merge_kernel<<<N / 256, 256, 0, stream>>>(part_m, part_l, srow);
    pass2_mfma<<<1024, 256, 0, stream>>>(hHi, hLo, srow, out);
}